// Round 9
// baseline (296.369 us; speedup 1.0000x reference)
//
#include <hip/hip_runtime.h>
#include <stdint.h>

using f32x4  = __attribute__((ext_vector_type(4))) float;
using bf16x8 = __attribute__((ext_vector_type(8))) short;
using ushort8 = __attribute__((ext_vector_type(8))) unsigned short;

#define B_   16384
#define S_   256
#define DIN  2048
#define DFC  1024
#define NB_  10

// f32 -> bf16 round-to-nearest-even
__device__ __forceinline__ unsigned short f2bf(float f) {
  union { float f; unsigned int u; } v; v.f = f;
  unsigned int u = v.u;
  unsigned int r = (u + 0x7FFFu + ((u >> 16) & 1u)) >> 16;
  return (unsigned short)r;
}

// async global->LDS, 16B per lane. LDS dest is wave-uniform base + lane*16.
__device__ __forceinline__ void gload_lds16(const void* g, void* l) {
  __builtin_amdgcn_global_load_lds(
      (const __attribute__((address_space(1))) unsigned int*)g,
      (__attribute__((address_space(3))) unsigned int*)l, 16, 0, 0);
}

// ---------------- K0: W1 (f32, [K=2048][N=1024]) -> Wt (bf16, [N][K]) ----------------
__global__ __launch_bounds__(256)
void convT_kernel(const float* __restrict__ W, unsigned short* __restrict__ Wt) {
  __shared__ unsigned short t[32][33];
  const int tx = threadIdx.x & 31;
  const int ty = threadIdx.x >> 5;          // 0..7
  const int nb = blockIdx.x * 32;           // n base
  const int kb = blockIdx.y * 32;           // k base
#pragma unroll
  for (int i = 0; i < 32; i += 8)
    t[ty + i][tx] = f2bf(W[(size_t)(kb + ty + i) * DFC + nb + tx]);
  __syncthreads();
#pragma unroll
  for (int i = 0; i < 32; i += 8)
    Wt[(size_t)(nb + ty + i) * DIN + kb + tx] = t[tx][ty + i];
}

// ---------------- K1: x = elu(A @ Wt^T + b1), stored bf16 ----------------
// r2-proven structure: 128x128 tile, BK=64, 4 waves (2x2 of 64x64), single
// LDS buffer, 2 __syncthreads per K-step, conflict-free XOR-chunk layout
// (chunk position p of row r holds k-chunk c = p ^ (r&7)).
// NEW: A conversion fused — A loaded f32 to registers (issued BEFORE B's
// gload_lds so cvt's vmcnt wait doesn't drain the async queue), converted
// via v_cvt_pk_bf16_f32, scattered to the swizzled layout with ds_write_b128
// (2 lanes/bank-quad per quarter-wave = free). B staged via gload_lds with
// inverse-swizzled global source as before. Eliminates the convA kernel.
__global__ __launch_bounds__(256)
void gemm1_kernel(const float* __restrict__ A, const unsigned short* __restrict__ Bt,
                  const float* __restrict__ b1, unsigned short* __restrict__ X) {
  __shared__ unsigned short sA[128 * 64];   // 16KB bf16, ds_write staged (swizzled)
  __shared__ unsigned short sB[128 * 64];   // 16KB bf16, gload_lds staged
  const int tid  = threadIdx.x;
  const int wave = tid >> 6, lane = tid & 63;
  // XCD-chunked swizzle: 8 consecutive slots (sharing one A row-panel) -> same XCD.
  const int b    = blockIdx.x;              // 1024 blocks
  const int xcd  = b & 7, slot = b >> 3;
  const int mtile = xcd * 16 + (slot >> 3); // 0..127
  const int ntile = slot & 7;               // 0..7
  const int rowBase = mtile * 128, colBase = ntile * 128;
  const int wr = wave >> 1, wc = wave & 1;

  f32x4 acc[4][4] = {};

  // B staging source (inverse swizzle), as r2
  const int srow = wave * 32 + (lane >> 3);
  const int schk = (lane & 7) ^ (lane >> 3);
  const unsigned short* pB = Bt + (size_t)(colBase + srow) * DIN + schk * 8;

  // A staging: thread covers row ar = tid/2, k-half ah (32 f32 = 128B)
  const int ar = tid >> 1, ah = tid & 1;
  const float* pA = A + (size_t)(rowBase + ar) * DIN + ah * 32;

  const int frow = lane & 15, hi = lane >> 4, s7 = frow & 7;

  for (int kk = 0; kk < DIN; kk += 64) {
    // A f32 reg loads FIRST (so B gloads below are newer in the vmem queue)
    f32x4 av[8];
#pragma unroll
    for (int i = 0; i < 8; ++i)
      av[i] = *(const f32x4*)(pA + kk + i * 4);
    // B async staging
#pragma unroll
    for (int j = 0; j < 4; ++j)
      gload_lds16(pB + kk + (size_t)j * 8 * DIN, &sB[(wave * 4 + j) * 512]);
    // A convert + swizzled ds_write (chunk c = ah*4+i at position c^(ar&7))
#pragma unroll
    for (int i = 0; i < 4; ++i) {
      union { bf16x8 h; uint32_t u[4]; } o;
      asm("v_cvt_pk_bf16_f32 %0, %1, %2" : "=v"(o.u[0]) : "v"(av[2*i][0]),   "v"(av[2*i][1]));
      asm("v_cvt_pk_bf16_f32 %0, %1, %2" : "=v"(o.u[1]) : "v"(av[2*i][2]),   "v"(av[2*i][3]));
      asm("v_cvt_pk_bf16_f32 %0, %1, %2" : "=v"(o.u[2]) : "v"(av[2*i+1][0]), "v"(av[2*i+1][1]));
      asm("v_cvt_pk_bf16_f32 %0, %1, %2" : "=v"(o.u[3]) : "v"(av[2*i+1][2]), "v"(av[2*i+1][3]));
      const int chk = (ah * 4 + i) ^ (ar & 7);
      *(bf16x8*)&sA[ar * 64 + chk * 8] = o.h;
    }
    __syncthreads();
#pragma unroll
    for (int ks = 0; ks < 2; ++ks) {
      const int rchk = ((ks * 4 + hi) ^ s7) * 8;
      bf16x8 af[4], bfr[4];
#pragma unroll
      for (int m = 0; m < 4; ++m)
        af[m] = *(const bf16x8*)&sA[(wr * 64 + m * 16 + frow) * 64 + rchk];
#pragma unroll
      for (int n = 0; n < 4; ++n)
        bfr[n] = *(const bf16x8*)&sB[(wc * 64 + n * 16 + frow) * 64 + rchk];
#pragma unroll
      for (int m = 0; m < 4; ++m)
#pragma unroll
        for (int n = 0; n < 4; ++n)
          acc[m][n] = __builtin_amdgcn_mfma_f32_16x16x32_bf16(af[m], bfr[n], acc[m][n], 0, 0, 0);
    }
    __syncthreads();
  }

  // epilogue: C/D layout col = lane&15, row = (lane>>4)*4 + reg
  const int er0 = rowBase + wr * 64 + hi * 4;
  const int ec0 = colBase + wc * 64 + frow;
  float bv[4];
#pragma unroll
  for (int n = 0; n < 4; ++n) bv[n] = b1[ec0 + n * 16];
#pragma unroll
  for (int m = 0; m < 4; ++m)
#pragma unroll
    for (int n = 0; n < 4; ++n)
#pragma unroll
      for (int r = 0; r < 4; ++r) {
        float v = acc[m][n][r] + bv[n];
        v = v > 0.f ? v : expm1f(v);
        X[(size_t)(er0 + m * 16 + r) * DFC + ec0 + n * 16] = f2bf(v);
      }
}

// ---------------- K2: shape_params = x @ w_shape + b_shape -> d_out (mode | log_std) ----------------
__global__ __launch_bounds__(256)
void gemm2_kernel(const unsigned short* __restrict__ X, const float* __restrict__ Wsh,
                  const float* __restrict__ bsh, float* __restrict__ out) {
  __shared__ unsigned short sX[64 * 32];    // linear for global_load_lds
  __shared__ unsigned short sW[32 * 40];    // [j][k] stride 40 (80B)
  const int tid  = threadIdx.x;
  const int wave = tid >> 6, lane = tid & 63;
  const int rowB = blockIdx.x * 64;
  f32x4 acc[2] = {};
  const unsigned short* xp = X + (size_t)(rowB + (tid >> 2)) * DFC + (tid & 3) * 8;
  unsigned short* sXb = &sX[wave * 512];
  const int frow = lane & 15, fks = (lane >> 4) * 8;

  for (int kk = 0; kk < DFC; kk += 32) {
    gload_lds16(xp + kk, sXb);
    for (int idx = tid; idx < 32 * 40; idx += 256) {
      int j = idx / 40, ki = idx - j * 40;
      sW[idx] = (j < 20 && ki < 32) ? f2bf(Wsh[(size_t)(kk + ki) * 20 + j]) : (unsigned short)0;
    }
    __syncthreads();
    bf16x8 xa  = *(const bf16x8*)&sX[(wave * 16 + frow) * 32 + fks];
    bf16x8 w0  = *(const bf16x8*)&sW[(frow) * 40 + fks];
    bf16x8 w1f = *(const bf16x8*)&sW[(16 + frow) * 40 + fks];
    acc[0] = __builtin_amdgcn_mfma_f32_16x16x32_bf16(xa, w0,  acc[0], 0, 0, 0);
    acc[1] = __builtin_amdgcn_mfma_f32_16x16x32_bf16(xa, w1f, acc[1], 0, 0, 0);
    __syncthreads();
  }
  const int r0 = rowB + wave * 16 + (lane >> 4) * 4;
  const int c0 = lane & 15;
#pragma unroll
  for (int n = 0; n < 2; ++n) {
    int j = n * 16 + c0;
    if (j < 20) {
      float bj = bsh[j];
      int jj = j < 10 ? j : j - 10;
      size_t base = (j < 10) ? (size_t)0 : (size_t)B_ * NB_;
#pragma unroll
      for (int r = 0; r < 4; ++r)
        out[base + (size_t)(r0 + r) * NB_ + jj] = acc[n][r] + bj;
    }
  }
}

// ---------------- K3: samples = mode + exp(log_std) * noise ----------------
// one wave per row; float4 loads/stores; mode/exp(ls) broadcast from tiny LDS arrays.
__global__ __launch_bounds__(256)
void sample_kernel(const float* __restrict__ noise, float* __restrict__ out) {
  __shared__ float sm[4][NB_], se[4][NB_];
  const int tid  = threadIdx.x;
  const int wave = tid >> 6, lane = tid & 63;
  const int row  = blockIdx.x * 4 + wave;
  if (lane < NB_) {
    sm[wave][lane] = out[(size_t)row * NB_ + lane];
    se[wave][lane] = expf(out[(size_t)B_ * NB_ + (size_t)row * NB_ + lane]);
  }
  __syncthreads();
  const f32x4* np4 = (const f32x4*)(noise + (size_t)row * (S_ * NB_));
  f32x4*       op4 = (f32x4*)(out + (size_t)2 * B_ * NB_ + (size_t)row * (S_ * NB_));
#pragma unroll
  for (int it = 0; it < (S_ * NB_) / 256; ++it) {   // 10 iters
    f32x4 nv = np4[it * 64 + lane];
    int j0 = (lane * 4 + it * 6) % 10;
    int j1 = j0 + 1; if (j1 >= 10) j1 -= 10;
    int j2 = j1 + 1; if (j2 >= 10) j2 -= 10;
    int j3 = j2 + 1; if (j3 >= 10) j3 -= 10;
    f32x4 r;
    r[0] = sm[wave][j0] + se[wave][j0] * nv[0];
    r[1] = sm[wave][j1] + se[wave][j1] * nv[1];
    r[2] = sm[wave][j2] + se[wave][j2] * nv[2];
    r[3] = sm[wave][j3] + se[wave][j3] * nv[3];
    op4[it * 64 + lane] = r;
  }
}

extern "C" void kernel_launch(void* const* d_in, const int* in_sizes, int n_in,
                              void* d_out, int out_size, void* d_ws, size_t ws_size,
                              hipStream_t stream) {
  const float* A     = (const float*)d_in[0];  // [16384][2048]
  const float* W1    = (const float*)d_in[1];  // [2048][1024]
  const float* b1    = (const float*)d_in[2];  // [1024]
  const float* Wsh   = (const float*)d_in[3];  // [1024][20]
  const float* bsh   = (const float*)d_in[4];  // [20]
  const float* noise = (const float*)d_in[5];  // [16384][256][10]
  float* out = (float*)d_out;                  // mode | log_std | samples

  unsigned short* Wt = (unsigned short*)d_ws;                      // bf16 [1024][2048] = 4 MB
  unsigned short* X  = (unsigned short*)d_ws + (size_t)DFC * DIN;  // bf16 [16384][1024] = 33.5 MB

  convT_kernel<<<dim3(DFC / 32, DIN / 32), 256, 0, stream>>>(W1, Wt);
  gemm1_kernel<<<dim3((B_ / 128) * (DFC / 128)), 256, 0, stream>>>(A, Wt, b1, X);
  gemm2_kernel<<<dim3(B_ / 64), 256, 0, stream>>>(X, Wsh, bsh, out);
  sample_kernel<<<dim3(B_ / 4), 256, 0, stream>>>(noise, out);
}

// Round 10
// 229.907 us; speedup vs baseline: 1.2891x; 1.2891x over previous
//
#include <hip/hip_runtime.h>
#include <stdint.h>

using f32x4  = __attribute__((ext_vector_type(4))) float;
using bf16x8 = __attribute__((ext_vector_type(8))) short;
using ushort8 = __attribute__((ext_vector_type(8))) unsigned short;

#define B_   16384
#define S_   256
#define DIN  2048
#define DFC  1024
#define NB_  10

// f32 -> bf16 round-to-nearest-even
__device__ __forceinline__ unsigned short f2bf(float f) {
  union { float f; unsigned int u; } v; v.f = f;
  unsigned int u = v.u;
  unsigned int r = (u + 0x7FFFu + ((u >> 16) & 1u)) >> 16;
  return (unsigned short)r;
}

// async global->LDS, 16B per lane. LDS dest is wave-uniform base + lane*16;
// global source address is per-lane.
__device__ __forceinline__ void gload_lds16(const void* g, void* l) {
  __builtin_amdgcn_global_load_lds(
      (const __attribute__((address_space(1))) unsigned int*)g,
      (__attribute__((address_space(3))) unsigned int*)l, 16, 0, 0);
}

// ---------------- K0a: W1 (f32, [K=2048][N=1024]) -> Wt (bf16, [N][K]) ----------------
__global__ __launch_bounds__(256)
void convT_kernel(const float* __restrict__ W, unsigned short* __restrict__ Wt) {
  __shared__ unsigned short t[32][33];
  const int tx = threadIdx.x & 31;
  const int ty = threadIdx.x >> 5;          // 0..7
  const int nb = blockIdx.x * 32;           // n base
  const int kb = blockIdx.y * 32;           // k base
#pragma unroll
  for (int i = 0; i < 32; i += 8)
    t[ty + i][tx] = f2bf(W[(size_t)(kb + ty + i) * DFC + nb + tx]);
  __syncthreads();
#pragma unroll
  for (int i = 0; i < 32; i += 8)
    Wt[(size_t)(nb + ty + i) * DIN + kb + tx] = t[tx][ty + i];
}

// ---------------- K0b: Wsh (f32 [1024][20]) -> WshT (bf16 [32][1024], j-major, rows>=20 zero) ----
__global__ __launch_bounds__(256)
void convW2_kernel(const float* __restrict__ Wsh, unsigned short* __restrict__ WshT) {
  const int idx = blockIdx.x * 256 + threadIdx.x;   // 128 blocks -> 32768
  const int j = idx >> 10, k = idx & 1023;
  WshT[idx] = (j < 20) ? f2bf(Wsh[(size_t)k * 20 + j]) : (unsigned short)0;
}

// ---------------- K0c: A (f32 [16384][2048]) -> Ab (bf16, same layout) ----------------
__global__ __launch_bounds__(256)
void convA_kernel(const float* __restrict__ A, unsigned short* __restrict__ Ab) {
  const size_t total = (size_t)B_ * DIN;
  size_t idx = ((size_t)blockIdx.x * 256 + threadIdx.x) * 8;
  const size_t stride = (size_t)gridDim.x * 256 * 8;
  for (; idx < total; idx += stride) {
    f32x4 a = *(const f32x4*)(A + idx);
    f32x4 b = *(const f32x4*)(A + idx + 4);
    ushort8 o;
    o[0] = f2bf(a[0]); o[1] = f2bf(a[1]); o[2] = f2bf(a[2]); o[3] = f2bf(a[3]);
    o[4] = f2bf(b[0]); o[5] = f2bf(b[1]); o[6] = f2bf(b[2]); o[7] = f2bf(b[3]);
    *(ushort8*)(Ab + idx) = o;
  }
}

// ---------------- K1: x = elu(Ab @ Wt^T + b1), stored bf16 (r5-best source) ----------------
__global__ __launch_bounds__(512, 2)
void gemm1_kernel(const unsigned short* __restrict__ Ab, const unsigned short* __restrict__ Bt,
                  const float* __restrict__ b1, unsigned short* __restrict__ X) {
  __shared__ unsigned short sT[2][2][2][8192];  // [dbuf][A=0/B=1][ks] 128KB
  const int tid  = threadIdx.x;
  const int wave = tid >> 6, lane = tid & 63;
  const int wm = wave >> 2, wn = wave & 3;      // 2M x 4N waves, wave tile 128x64
  const int b = blockIdx.x;                     // 256 blocks
  const int tile = (b & 7) * 32 + (b >> 3);     // XCD-chunked bijection
  const int mtile = tile >> 2, ntile = tile & 3;
  const int rowBase = mtile * 256, colBase = ntile * 256;

  f32x4 acc[8][4] = {};

  const int lrow0 = wave * 16 + (lane >> 3);
  const int q     = (lane & 7) ^ (lrow0 & 7);
  const unsigned short* gA = Ab + (size_t)(rowBase + lrow0 * 2 + (q >> 2)) * DIN + (q & 3) * 8;
  const unsigned short* gB = Bt + (size_t)(colBase + lrow0 * 2 + (q >> 2)) * DIN + (q & 3) * 8;
  const int ldOff = wave * 1024;

  const int frow = lane & 15, hi = lane >> 4, fr2 = frow >> 1;
  const int pp    = ((frow & 1) * 4 + hi) ^ fr2;
  const int aBase = (wm * 64 + fr2) * 64 + pp * 8;
  const int bBase = (wn * 32 + fr2) * 64 + pp * 8;

#define STAGE(opv, db, ksv, kt) do {                                        \
    const unsigned short* g_ = ((opv) ? gB : gA) + (kt) * 64 + (ksv) * 32;  \
    unsigned short* l_ = &sT[db][opv][ksv][ldOff];                          \
    gload_lds16(g_, l_);                                                    \
    gload_lds16(g_ + (size_t)16 * DIN, l_ + 512);                           \
  } while (0)

  bf16x8 afr[4], bfr[4];
#define READ_B(db, ksv) do {                                                \
    const unsigned short* s_ = &sT[db][1][ksv][bBase];                      \
    bfr[0] = *(const bf16x8*)(s_);        bfr[1] = *(const bf16x8*)(s_ + 512); \
    bfr[2] = *(const bf16x8*)(s_ + 1024); bfr[3] = *(const bf16x8*)(s_ + 1536); \
  } while (0)
#define READ_A(db, ksv, mq) do {                                            \
    const unsigned short* s_ = &sT[db][0][ksv][aBase + (mq) * 2048];        \
    afr[0] = *(const bf16x8*)(s_);        afr[1] = *(const bf16x8*)(s_ + 512); \
    afr[2] = *(const bf16x8*)(s_ + 1024); afr[3] = *(const bf16x8*)(s_ + 1536); \
  } while (0)
#define MFMA16(mq) do {                                                     \
    __builtin_amdgcn_s_setprio(1);                                          \
    _Pragma("unroll") for (int m_ = 0; m_ < 4; ++m_)                        \
      _Pragma("unroll") for (int n_ = 0; n_ < 4; ++n_)                      \
        acc[(mq) * 4 + m_][n_] = __builtin_amdgcn_mfma_f32_16x16x32_bf16(   \
            afr[m_], bfr[n_], acc[(mq) * 4 + m_][n_], 0, 0, 0);             \
    __builtin_amdgcn_s_setprio(0);                                          \
  } while (0)
#define FENCE asm volatile("" ::: "memory")
#define BAR do { FENCE; __builtin_amdgcn_s_barrier(); FENCE; } while (0)

  STAGE(0, 0, 0, 0); STAGE(1, 0, 0, 0); STAGE(0, 0, 1, 0); STAGE(1, 0, 1, 0);
  STAGE(0, 1, 0, 1); STAGE(1, 1, 0, 1);

  const int NT = DIN / 64;  // 32
#pragma unroll 2
  for (int k = 0; k < NT - 1; ++k) {
    const int db = k & 1, dn = db ^ 1;
    asm volatile("s_waitcnt vmcnt(8)" ::: "memory");
    BAR;
    READ_B(db, 0); READ_A(db, 0, 0);
    STAGE(0, dn, 1, k + 1);
    MFMA16(0);
    BAR;
    READ_A(db, 0, 1);
    STAGE(1, dn, 1, k + 1);
    MFMA16(1);
    asm volatile("s_waitcnt vmcnt(8)" ::: "memory");
    BAR;
    READ_B(db, 1); READ_A(db, 1, 0);
    if (k < NT - 2) STAGE(0, db, 0, k + 2);
    MFMA16(0);
    BAR;
    READ_A(db, 1, 1);
    if (k < NT - 2) STAGE(1, db, 0, k + 2);
    MFMA16(1);
  }
  {  // peeled last tile
    const int db = (NT - 1) & 1;
    asm volatile("s_waitcnt vmcnt(4)" ::: "memory");
    BAR;
    READ_B(db, 0); READ_A(db, 0, 0);
    MFMA16(0);
    BAR;
    READ_A(db, 0, 1);
    MFMA16(1);
    asm volatile("s_waitcnt vmcnt(0)" ::: "memory");
    BAR;
    READ_B(db, 1); READ_A(db, 1, 0);
    MFMA16(0);
    BAR;
    READ_A(db, 1, 1);
    MFMA16(1);
  }
#undef STAGE
#undef READ_A
#undef READ_B
#undef MFMA16

  const int er0 = rowBase + wm * 128 + hi * 4;
  const int ec0 = colBase + wn * 64 + frow;
  float bv[4];
#pragma unroll
  for (int n = 0; n < 4; ++n) bv[n] = b1[ec0 + n * 16];
#pragma unroll
  for (int m = 0; m < 8; ++m)
#pragma unroll
    for (int n = 0; n < 4; ++n)
#pragma unroll
      for (int r = 0; r < 4; ++r) {
        float v = acc[m][n][r] + bv[n];
        v = v > 0.f ? v : expm1f(v);
        X[(size_t)(er0 + m * 16 + r) * DFC + ec0 + n * 16] = f2bf(v);
      }
}

// ---------------- K2: shape_params = x @ w_shape + b_shape -> d_out (mode | log_std) ----------------
// 512 blocks x 32 rows, 4 waves = (row-half rh) x (k-half kh). Whole X-tile
// (64KB) staged upfront (16 gload_lds/thread, swizzled pos p holds chunk
// p^(r&7)), ONE barrier; B-frags read straight from L2-resident WshT bf16;
// 16-step MFMA loop has no syncs; cross-kh reduce via small LDS.
__global__ __launch_bounds__(256)
void gemm2_kernel(const unsigned short* __restrict__ X, const unsigned short* __restrict__ WshT,
                  const float* __restrict__ bsh, float* __restrict__ out) {
  __shared__ unsigned short sX[32 * 1024];   // 64KB
  __shared__ float sRed[32][22];
  const int tid = threadIdx.x, wave = tid >> 6, lane = tid & 63;
  const int rh = wave & 1, kh = wave >> 1;
  const int rowB = blockIdx.x * 32;
  const int frow = lane & 15, hi = lane >> 4;

  // stage X tile: instr ji covers chunks [ji*64, +64); lane l -> chunk ji*64+l
  // dest row r = ji>>1 (uniform/instr), dest pos ph = (ji&1)*64 + l,
  // source chunk c = ph ^ (r&7) (involution, low 3 bits).
#pragma unroll
  for (int i = 0; i < 16; ++i) {
    const int ji = wave * 16 + i;
    const int r  = ji >> 1;
    const int ph = (ji & 1) * 64 + lane;
    const int c  = ph ^ (r & 7);
    gload_lds16(X + (size_t)(rowB + r) * DFC + c * 8, &sX[ji * 512]);
  }
  asm volatile("s_waitcnt vmcnt(0)" ::: "memory");
  __syncthreads();

  f32x4 acc[2] = {};
  const int arow = rh * 16 + frow;
  const unsigned short* bp0 = WshT + (size_t)frow * DFC + kh * 512 + hi * 8;
  const unsigned short* bp1 = WshT + (size_t)(16 + frow) * DFC + kh * 512 + hi * 8;
#pragma unroll
  for (int s = 0; s < 16; ++s) {
    const int c = kh * 64 + s * 4 + hi;          // global k-chunk
    const int p = c ^ (arow & 7);
    bf16x8 xa = *(const bf16x8*)&sX[arow * 1024 + p * 8];
    bf16x8 b0 = *(const bf16x8*)(bp0 + s * 32);
    bf16x8 b1 = *(const bf16x8*)(bp1 + s * 32);
    acc[0] = __builtin_amdgcn_mfma_f32_16x16x32_bf16(xa, b0, acc[0], 0, 0, 0);
    acc[1] = __builtin_amdgcn_mfma_f32_16x16x32_bf16(xa, b1, acc[1], 0, 0, 0);
  }

  // C/D layout: col = lane&15 (=frow), local row = rh*16 + hi*4 + r
  const int r0l = rh * 16 + hi * 4;
  if (kh == 1) {
#pragma unroll
    for (int n = 0; n < 2; ++n) {
      const int j = n * 16 + frow;
      if (j < 20)
#pragma unroll
        for (int r = 0; r < 4; ++r)
          sRed[r0l + r][j] = acc[n][r];
    }
  }
  __syncthreads();
  if (kh == 0) {
#pragma unroll
    for (int n = 0; n < 2; ++n) {
      const int j = n * 16 + frow;
      if (j < 20) {
        const float bj = bsh[j];
        const int jj = j < 10 ? j : j - 10;
        const size_t base = (j < 10) ? (size_t)0 : (size_t)B_ * NB_;
#pragma unroll
        for (int r = 0; r < 4; ++r)
          out[base + (size_t)(rowB + r0l + r) * NB_ + jj] = acc[n][r] + sRed[r0l + r][j] + bj;
      }
    }
  }
}

// ---------------- K3: samples = mode + exp(log_std) * noise ----------------
__global__ __launch_bounds__(256)
void sample_kernel(const float* __restrict__ noise, float* __restrict__ out) {
  __shared__ float sm[4][NB_], se[4][NB_];
  const int tid  = threadIdx.x;
  const int wave = tid >> 6, lane = tid & 63;
  const int row  = blockIdx.x * 4 + wave;
  if (lane < NB_) {
    sm[wave][lane] = out[(size_t)row * NB_ + lane];
    se[wave][lane] = expf(out[(size_t)B_ * NB_ + (size_t)row * NB_ + lane]);
  }
  __syncthreads();
  const f32x4* np4 = (const f32x4*)(noise + (size_t)row * (S_ * NB_));
  f32x4*       op4 = (f32x4*)(out + (size_t)2 * B_ * NB_ + (size_t)row * (S_ * NB_));
#pragma unroll
  for (int it = 0; it < (S_ * NB_) / 256; ++it) {   // 10 iters
    f32x4 nv = np4[it * 64 + lane];
    int j0 = (lane * 4 + it * 6) % 10;
    int j1 = j0 + 1; if (j1 >= 10) j1 -= 10;
    int j2 = j1 + 1; if (j2 >= 10) j2 -= 10;
    int j3 = j2 + 1; if (j3 >= 10) j3 -= 10;
    f32x4 r;
    r[0] = sm[wave][j0] + se[wave][j0] * nv[0];
    r[1] = sm[wave][j1] + se[wave][j1] * nv[1];
    r[2] = sm[wave][j2] + se[wave][j2] * nv[2];
    r[3] = sm[wave][j3] + se[wave][j3] * nv[3];
    op4[it * 64 + lane] = r;
  }
}

extern "C" void kernel_launch(void* const* d_in, const int* in_sizes, int n_in,
                              void* d_out, int out_size, void* d_ws, size_t ws_size,
                              hipStream_t stream) {
  const float* A     = (const float*)d_in[0];  // [16384][2048]
  const float* W1    = (const float*)d_in[1];  // [2048][1024]
  const float* b1    = (const float*)d_in[2];  // [1024]
  const float* Wsh   = (const float*)d_in[3];  // [1024][20]
  const float* bsh   = (const float*)d_in[4];  // [20]
  const float* noise = (const float*)d_in[5];  // [16384][256][10]
  float* out = (float*)d_out;                  // mode | log_std | samples

  unsigned short* Wt   = (unsigned short*)d_ws;                            // 2M elems
  unsigned short* X    = Wt + (size_t)DFC * DIN;                           // 16.8M elems
  unsigned short* WshT = X + (size_t)B_ * DFC;                             // 32K elems
  // Ab (bf16 A, 64 MB): ws if it fits, else stash in d_out's samples region
  // (written before gemm1 reads it, overwritten by sample_kernel at the end).
  const size_t wsNeed = ((size_t)DFC * DIN + (size_t)B_ * DFC + 32 * 1024 + (size_t)B_ * DIN) * 2;
  unsigned short* Ab = (ws_size >= wsNeed)
      ? WshT + (size_t)32 * 1024
      : (unsigned short*)(out + (size_t)2 * B_ * NB_);

  convT_kernel<<<dim3(DFC / 32, DIN / 32), 256, 0, stream>>>(W1, Wt);
  convW2_kernel<<<dim3(128), 256, 0, stream>>>(Wsh, WshT);
  convA_kernel<<<dim3(2048), 256, 0, stream>>>(A, Ab);
  gemm1_kernel<<<dim3((B_ / 256) * (DFC / 256)), 512, 0, stream>>>(Ab, Wt, b1, X);
  gemm2_kernel<<<dim3(B_ / 32), 256, 0, stream>>>(X, WshT, bsh, out);
  sample_kernel<<<dim3(B_ / 4), 256, 0, stream>>>(noise, out);
}

// Round 11
// 199.173 us; speedup vs baseline: 1.4880x; 1.1543x over previous
//
#include <hip/hip_runtime.h>
#include <stdint.h>

using f32x4  = __attribute__((ext_vector_type(4))) float;
using bf16x8 = __attribute__((ext_vector_type(8))) short;
using ushort8 = __attribute__((ext_vector_type(8))) unsigned short;

#define B_   16384
#define S_   256
#define DIN  2048
#define DFC  1024
#define NB_  10

// f32 -> bf16 round-to-nearest-even
__device__ __forceinline__ unsigned short f2bf(float f) {
  union { float f; unsigned int u; } v; v.f = f;
  unsigned int u = v.u;
  unsigned int r = (u + 0x7FFFu + ((u >> 16) & 1u)) >> 16;
  return (unsigned short)r;
}

// async global->LDS, 16B per lane. LDS dest is wave-uniform base + lane*16;
// global source address is per-lane.
__device__ __forceinline__ void gload_lds16(const void* g, void* l) {
  __builtin_amdgcn_global_load_lds(
      (const __attribute__((address_space(1))) unsigned int*)g,
      (__attribute__((address_space(3))) unsigned int*)l, 16, 0, 0);
}

// epilogue-LDS swizzle: chunk c of row r stored at pos c ^ SW(r&15).
// SW spreads 4 row-bits + 2 hi-bits into 5-bit positions with exactly
// 2 lanes per position on every read/write instruction (2-way = free).
__device__ __forceinline__ int SW(int r) {
  return ((r & 3) << 3) | (r & 4) | ((r >> 3) * 3);
}

// ---------------- K0a: W1 (f32, [K=2048][N=1024]) -> Wt (bf16, [N][K]) ----------------
__global__ __launch_bounds__(256)
void convT_kernel(const float* __restrict__ W, unsigned short* __restrict__ Wt) {
  __shared__ unsigned short t[32][33];
  const int tx = threadIdx.x & 31;
  const int ty = threadIdx.x >> 5;          // 0..7
  const int nb = blockIdx.x * 32;           // n base
  const int kb = blockIdx.y * 32;           // k base
#pragma unroll
  for (int i = 0; i < 32; i += 8)
    t[ty + i][tx] = f2bf(W[(size_t)(kb + ty + i) * DFC + nb + tx]);
  __syncthreads();
#pragma unroll
  for (int i = 0; i < 32; i += 8)
    Wt[(size_t)(nb + ty + i) * DIN + kb + tx] = t[tx][ty + i];
}

// ---------------- K0b: Wsh (f32 [1024][20]) -> WshT (bf16 [32][1024], rows>=20 zero) ----
__global__ __launch_bounds__(256)
void convW2_kernel(const float* __restrict__ Wsh, unsigned short* __restrict__ WshT) {
  const int idx = blockIdx.x * 256 + threadIdx.x;   // 128 blocks -> 32768
  const int j = idx >> 10, k = idx & 1023;
  WshT[idx] = (j < 20) ? f2bf(Wsh[(size_t)k * 20 + j]) : (unsigned short)0;
}

// ---------------- K0c: A (f32 [16384][2048]) -> Ab (bf16, same layout) ----------------
__global__ __launch_bounds__(256)
void convA_kernel(const float* __restrict__ A, unsigned short* __restrict__ Ab) {
  const size_t total = (size_t)B_ * DIN;
  size_t idx = ((size_t)blockIdx.x * 256 + threadIdx.x) * 8;
  const size_t stride = (size_t)gridDim.x * 256 * 8;
  for (; idx < total; idx += stride) {
    f32x4 a = *(const f32x4*)(A + idx);
    f32x4 b = *(const f32x4*)(A + idx + 4);
    ushort8 o;
    o[0] = f2bf(a[0]); o[1] = f2bf(a[1]); o[2] = f2bf(a[2]); o[3] = f2bf(a[3]);
    o[4] = f2bf(b[0]); o[5] = f2bf(b[1]); o[6] = f2bf(b[2]); o[7] = f2bf(b[3]);
    *(ushort8*)(Ab + idx) = o;
  }
}

// ---------------- K1: x = elu(Ab @ Wt^T + b1); fused partial x@Wsh ----------------
// Main loop: r5-best source (256x256 tile, 8 waves, BK=64, 4-phase, vmcnt(8)).
// Epilogue: x never hits HBM — per 128-row half, x-bf16 goes to reused sT LDS
// (swizzled), 16 MFMA/wave mini-GEMM vs WshT k-slice, 256x20 f32 partial out.
__global__ __launch_bounds__(512, 2)
void gemm1_kernel(const unsigned short* __restrict__ Ab, const unsigned short* __restrict__ Bt,
                  const unsigned short* __restrict__ WshT, const float* __restrict__ b1,
                  float* __restrict__ part) {
  __shared__ unsigned short sT[2][2][2][8192];  // [dbuf][A=0/B=1][ks] 128KB
  const int tid  = threadIdx.x;
  const int wave = tid >> 6, lane = tid & 63;
  const int wm = wave >> 2, wn = wave & 3;      // 2M x 4N waves, wave tile 128x64
  const int b = blockIdx.x;                     // 256 blocks
  const int tile = (b & 7) * 32 + (b >> 3);     // XCD-chunked bijection
  const int mtile = tile >> 2, ntile = tile & 3;
  const int rowBase = mtile * 256, colBase = ntile * 256;

  f32x4 acc[8][4] = {};

  const int lrow0 = wave * 16 + (lane >> 3);
  const int q     = (lane & 7) ^ (lrow0 & 7);
  const unsigned short* gA = Ab + (size_t)(rowBase + lrow0 * 2 + (q >> 2)) * DIN + (q & 3) * 8;
  const unsigned short* gB = Bt + (size_t)(colBase + lrow0 * 2 + (q >> 2)) * DIN + (q & 3) * 8;
  const int ldOff = wave * 1024;

  const int frow = lane & 15, hi = lane >> 4, fr2 = frow >> 1;
  const int pp    = ((frow & 1) * 4 + hi) ^ fr2;
  const int aBase = (wm * 64 + fr2) * 64 + pp * 8;
  const int bBase = (wn * 32 + fr2) * 64 + pp * 8;

#define STAGE(opv, db, ksv, kt) do {                                        \
    const unsigned short* g_ = ((opv) ? gB : gA) + (kt) * 64 + (ksv) * 32;  \
    unsigned short* l_ = &sT[db][opv][ksv][ldOff];                          \
    gload_lds16(g_, l_);                                                    \
    gload_lds16(g_ + (size_t)16 * DIN, l_ + 512);                           \
  } while (0)

  bf16x8 afr[4], bfr[4];
#define READ_B(db, ksv) do {                                                \
    const unsigned short* s_ = &sT[db][1][ksv][bBase];                      \
    bfr[0] = *(const bf16x8*)(s_);        bfr[1] = *(const bf16x8*)(s_ + 512); \
    bfr[2] = *(const bf16x8*)(s_ + 1024); bfr[3] = *(const bf16x8*)(s_ + 1536); \
  } while (0)
#define READ_A(db, ksv, mq) do {                                            \
    const unsigned short* s_ = &sT[db][0][ksv][aBase + (mq) * 2048];        \
    afr[0] = *(const bf16x8*)(s_);        afr[1] = *(const bf16x8*)(s_ + 512); \
    afr[2] = *(const bf16x8*)(s_ + 1024); afr[3] = *(const bf16x8*)(s_ + 1536); \
  } while (0)
#define MFMA16(mq) do {                                                     \
    __builtin_amdgcn_s_setprio(1);                                          \
    _Pragma("unroll") for (int m_ = 0; m_ < 4; ++m_)                        \
      _Pragma("unroll") for (int n_ = 0; n_ < 4; ++n_)                      \
        acc[(mq) * 4 + m_][n_] = __builtin_amdgcn_mfma_f32_16x16x32_bf16(   \
            afr[m_], bfr[n_], acc[(mq) * 4 + m_][n_], 0, 0, 0);             \
    __builtin_amdgcn_s_setprio(0);                                          \
  } while (0)
#define FENCE asm volatile("" ::: "memory")
#define BAR do { FENCE; __builtin_amdgcn_s_barrier(); FENCE; } while (0)

  STAGE(0, 0, 0, 0); STAGE(1, 0, 0, 0); STAGE(0, 0, 1, 0); STAGE(1, 0, 1, 0);
  STAGE(0, 1, 0, 1); STAGE(1, 1, 0, 1);

  const int NT = DIN / 64;  // 32
#pragma unroll 2
  for (int k = 0; k < NT - 1; ++k) {
    const int db = k & 1, dn = db ^ 1;
    asm volatile("s_waitcnt vmcnt(8)" ::: "memory");
    BAR;
    READ_B(db, 0); READ_A(db, 0, 0);
    STAGE(0, dn, 1, k + 1);
    MFMA16(0);
    BAR;
    READ_A(db, 0, 1);
    STAGE(1, dn, 1, k + 1);
    MFMA16(1);
    asm volatile("s_waitcnt vmcnt(8)" ::: "memory");
    BAR;
    READ_B(db, 1); READ_A(db, 1, 0);
    if (k < NT - 2) STAGE(0, db, 0, k + 2);
    MFMA16(0);
    BAR;
    READ_A(db, 1, 1);
    if (k < NT - 2) STAGE(1, db, 0, k + 2);
    MFMA16(1);
  }
  {  // peeled last tile
    const int db = (NT - 1) & 1;
    asm volatile("s_waitcnt vmcnt(4)" ::: "memory");
    BAR;
    READ_B(db, 0); READ_A(db, 0, 0);
    MFMA16(0);
    BAR;
    READ_A(db, 0, 1);
    MFMA16(1);
    asm volatile("s_waitcnt vmcnt(0)" ::: "memory");
    BAR;
    READ_B(db, 1); READ_A(db, 1, 0);
    MFMA16(0);
    BAR;
    READ_A(db, 1, 1);
    MFMA16(1);
  }
#undef STAGE
#undef READ_A
#undef READ_B
#undef MFMA16

  // ================= fused epilogue =================
  // C/D layout: col = lane&15 (=frow), row-in-frag = hi*4 + reg.
  const int ec0l = wn * 64 + frow;          // local col base of this wave's frags
  float bv[4];
#pragma unroll
  for (int n = 0; n < 4; ++n) bv[n] = b1[colBase + ec0l + n * 16];

  unsigned short* sX = (unsigned short*)sT;  // 64KB: [128 lrows][32 chunks of 8 bf16]
  BAR;  // main loop's trailing LDS reads are all complete after this

#pragma unroll
  for (int h = 0; h < 2; ++h) {
    // (a) write x-half (post-bias ELU, bf16) into swizzled sX
#pragma unroll
    for (int mm = 0; mm < 4; ++mm) {
#pragma unroll
      for (int n = 0; n < 4; ++n) {
#pragma unroll
        for (int r = 0; r < 4; ++r) {
          float v = acc[h * 4 + mm][n][r] + bv[n];
          v = v > 0.f ? v : expm1f(v);
          const int lrow = wm * 64 + mm * 16 + hi * 4 + r;   // 0..127
          const int cel  = ec0l + n * 16;                    // local col 0..255
          const int p    = (cel >> 3) ^ SW(lrow & 15);
          sX[lrow * 256 + p * 8 + (cel & 7)] = f2bf(v);
        }
      }
    }
    BAR;
    // (b) mini-GEMM: wave owns band `wave` (16 rows); k = this block's 256 cols
    f32x4 acc2[2] = {};
    const int rb = wave * 16;
#pragma unroll
    for (int ks = 0; ks < 8; ++ks) {
      const int p = (ks * 4 + hi) ^ SW(frow);
      bf16x8 xa = *(const bf16x8*)&sX[(rb + frow) * 256 + p * 8];
      bf16x8 w0 = *(const bf16x8*)(WshT + (size_t)frow * DFC + colBase + ks * 32 + hi * 8);
      bf16x8 w1 = *(const bf16x8*)(WshT + (size_t)(16 + frow) * DFC + colBase + ks * 32 + hi * 8);
      acc2[0] = __builtin_amdgcn_mfma_f32_16x16x32_bf16(xa, w0, acc2[0], 0, 0, 0);
      acc2[1] = __builtin_amdgcn_mfma_f32_16x16x32_bf16(xa, w1, acc2[1], 0, 0, 0);
    }
    // (c) store 16x20 partial (f32), rows of this band
#pragma unroll
    for (int jf = 0; jf < 2; ++jf) {
      const int j = jf * 16 + frow;
      if (j < 20) {
#pragma unroll
        for (int r = 0; r < 4; ++r) {
          const int lrow = rb + hi * 4 + r;                  // 0..127
          const int grow = rowBase + h * 64 + (lrow & 63) + (lrow >> 6) * 128;
          part[(size_t)ntile * (B_ * 20) + (size_t)grow * 20 + j] = acc2[jf][r];
        }
      }
    }
    BAR;  // reads of this half done before next half overwrites sX
  }
}

// ---------------- K2: reduce partials + bias -> d_out (mode | log_std) ----------------
__global__ __launch_bounds__(256)
void reduce2_kernel(const float* __restrict__ part, const float* __restrict__ bsh,
                    float* __restrict__ out) {
  const int idx = blockIdx.x * 256 + threadIdx.x;  // 1280 blocks x 256 = 327680
  if (idx >= B_ * 20) return;
  const int row = idx / 20, j = idx - row * 20;
  float s = bsh[j];
#pragma unroll
  for (int t = 0; t < 4; ++t) s += part[(size_t)t * (B_ * 20) + idx];
  const int jj = j < 10 ? j : j - 10;
  const size_t base = (j < 10) ? (size_t)0 : (size_t)B_ * NB_;
  out[base + (size_t)row * NB_ + jj] = s;
}

// ---------------- K3: samples = mode + exp(log_std) * noise ----------------
__global__ __launch_bounds__(256)
void sample_kernel(const float* __restrict__ noise, float* __restrict__ out) {
  __shared__ float sm[4][NB_], se[4][NB_];
  const int tid  = threadIdx.x;
  const int wave = tid >> 6, lane = tid & 63;
  const int row  = blockIdx.x * 4 + wave;
  if (lane < NB_) {
    sm[wave][lane] = out[(size_t)row * NB_ + lane];
    se[wave][lane] = expf(out[(size_t)B_ * NB_ + (size_t)row * NB_ + lane]);
  }
  __syncthreads();
  const f32x4* np4 = (const f32x4*)(noise + (size_t)row * (S_ * NB_));
  f32x4*       op4 = (f32x4*)(out + (size_t)2 * B_ * NB_ + (size_t)row * (S_ * NB_));
#pragma unroll
  for (int it = 0; it < (S_ * NB_) / 256; ++it) {   // 10 iters
    f32x4 nv = np4[it * 64 + lane];
    int j0 = (lane * 4 + it * 6) % 10;
    int j1 = j0 + 1; if (j1 >= 10) j1 -= 10;
    int j2 = j1 + 1; if (j2 >= 10) j2 -= 10;
    int j3 = j2 + 1; if (j3 >= 10) j3 -= 10;
    f32x4 r;
    r[0] = sm[wave][j0] + se[wave][j0] * nv[0];
    r[1] = sm[wave][j1] + se[wave][j1] * nv[1];
    r[2] = sm[wave][j2] + se[wave][j2] * nv[2];
    r[3] = sm[wave][j3] + se[wave][j3] * nv[3];
    op4[it * 64 + lane] = r;
  }
}

extern "C" void kernel_launch(void* const* d_in, const int* in_sizes, int n_in,
                              void* d_out, int out_size, void* d_ws, size_t ws_size,
                              hipStream_t stream) {
  const float* A     = (const float*)d_in[0];  // [16384][2048]
  const float* W1    = (const float*)d_in[1];  // [2048][1024]
  const float* b1    = (const float*)d_in[2];  // [1024]
  const float* Wsh   = (const float*)d_in[3];  // [1024][20]
  const float* bsh   = (const float*)d_in[4];  // [20]
  const float* noise = (const float*)d_in[5];  // [16384][256][10]
  float* out = (float*)d_out;                  // mode | log_std | samples

  unsigned short* Wt   = (unsigned short*)d_ws;        // bf16 [1024][2048] = 4 MB
  unsigned short* WshT = Wt + (size_t)DFC * DIN;       // bf16 [32][1024] = 64 KB
  // part (4 x 16384 x 20 f32 = 5.24 MB) + Ab (bf16 A, 67 MB): ws if it fits,
  // else both live in d_out's samples region (168 MB; written before gemm1
  // reads/writes them, fully overwritten by sample_kernel at the end).
  const size_t wsNeed = (size_t)DFC * DIN * 2 + 65536 +
                        (size_t)4 * B_ * 20 * 4 + (size_t)B_ * DIN * 2;
  float* part;
  unsigned short* Ab;
  if (ws_size >= wsNeed) {
    part = (float*)(WshT + 32 * 1024);
    Ab   = (unsigned short*)(part + (size_t)4 * B_ * 20);
  } else {
    part = out + (size_t)2 * B_ * NB_;
    Ab   = (unsigned short*)(part + (size_t)4 * B_ * 20);
  }

  convT_kernel<<<dim3(DFC / 32, DIN / 32), 256, 0, stream>>>(W1, Wt);
  convW2_kernel<<<dim3(128), 256, 0, stream>>>(Wsh, WshT);
  convA_kernel<<<dim3(2048), 256, 0, stream>>>(A, Ab);
  gemm1_kernel<<<dim3((B_ / 256) * (DFC / 256)), 512, 0, stream>>>(Ab, Wt, WshT, b1, part);
  reduce2_kernel<<<dim3((B_ * 20 + 255) / 256), 256, 0, stream>>>(part, bsh, out);
  sample_kernel<<<dim3(B_ / 4), 256, 0, stream>>>(noise, out);
}

// Round 12
// 182.679 us; speedup vs baseline: 1.6224x; 1.0903x over previous
//
#include <hip/hip_runtime.h>
#include <stdint.h>

using f32x4  = __attribute__((ext_vector_type(4))) float;
using bf16x8 = __attribute__((ext_vector_type(8))) short;
using ushort8 = __attribute__((ext_vector_type(8))) unsigned short;

#define B_   16384
#define S_   256
#define DIN  2048
#define DFC  1024
#define NB_  10

// f32 -> bf16 round-to-nearest-even
__device__ __forceinline__ unsigned short f2bf(float f) {
  union { float f; unsigned int u; } v; v.f = f;
  unsigned int u = v.u;
  unsigned int r = (u + 0x7FFFu + ((u >> 16) & 1u)) >> 16;
  return (unsigned short)r;
}

// async global->LDS, 16B per lane. LDS dest is wave-uniform base + lane*16;
// global source address is per-lane.
__device__ __forceinline__ void gload_lds16(const void* g, void* l) {
  __builtin_amdgcn_global_load_lds(
      (const __attribute__((address_space(1))) unsigned int*)g,
      (__attribute__((address_space(3))) unsigned int*)l, 16, 0, 0);
}

// epilogue-LDS swizzle (verified r11): chunk c of row r at pos c ^ SW(r&15).
__device__ __forceinline__ int SW(int r) {
  return ((r & 3) << 3) | (r & 4) | ((r >> 3) * 3);
}

// ---------------- K0a: W1 (f32, [K=2048][N=1024]) -> Wt (bf16, [N][K]) ----------------
__global__ __launch_bounds__(256)
void convT_kernel(const float* __restrict__ W, unsigned short* __restrict__ Wt) {
  __shared__ unsigned short t[32][33];
  const int tx = threadIdx.x & 31;
  const int ty = threadIdx.x >> 5;          // 0..7
  const int nb = blockIdx.x * 32;           // n base
  const int kb = blockIdx.y * 32;           // k base
#pragma unroll
  for (int i = 0; i < 32; i += 8)
    t[ty + i][tx] = f2bf(W[(size_t)(kb + ty + i) * DFC + nb + tx]);
  __syncthreads();
#pragma unroll
  for (int i = 0; i < 32; i += 8)
    Wt[(size_t)(nb + ty + i) * DIN + kb + tx] = t[tx][ty + i];
}

// ---------------- K0b: Wsh (f32 [1024][20]) -> WshT (bf16 [32][1024], rows>=20 zero) ----
__global__ __launch_bounds__(256)
void convW2_kernel(const float* __restrict__ Wsh, unsigned short* __restrict__ WshT) {
  const int idx = blockIdx.x * 256 + threadIdx.x;   // 128 blocks -> 32768
  const int j = idx >> 10, k = idx & 1023;
  WshT[idx] = (j < 20) ? f2bf(Wsh[(size_t)k * 20 + j]) : (unsigned short)0;
}

// ---------------- K0c: A (f32 [16384][2048]) -> Ab (bf16, same layout) ----------------
__global__ __launch_bounds__(256)
void convA_kernel(const float* __restrict__ A, unsigned short* __restrict__ Ab) {
  const size_t total = (size_t)B_ * DIN;
  size_t idx = ((size_t)blockIdx.x * 256 + threadIdx.x) * 8;
  const size_t stride = (size_t)gridDim.x * 256 * 8;
  for (; idx < total; idx += stride) {
    f32x4 a = *(const f32x4*)(A + idx);
    f32x4 b = *(const f32x4*)(A + idx + 4);
    ushort8 o;
    o[0] = f2bf(a[0]); o[1] = f2bf(a[1]); o[2] = f2bf(a[2]); o[3] = f2bf(a[3]);
    o[4] = f2bf(b[0]); o[5] = f2bf(b[1]); o[6] = f2bf(b[2]); o[7] = f2bf(b[3]);
    *(ushort8*)(Ab + idx) = o;
  }
}

// ---------------- K1: x = elu(Ab @ Wt^T + b1); fused partial x@Wsh ----------------
// 256x256 tile, 8 waves (2M x 4N), BK=64, dbuf ks-slices (128KB).
// Template-faithful phases: 4/tile, each {reads+stage -> BAR+sched_barrier ->
// setprio 16 MFMA (one quadrant x K=64) -> BAR}. Stages: P1/P2 = ks1(t+1),
// P4 = ks0(t+2) both ops (P3 reads ks0 so its stage moved to P4). Counted
// vmcnt(4) once/tile at P4 (drains ks1(t+1), leaves ks0(t+2) in flight).
// Epilogue (r11, verified): x stays on-chip; partial x@Wsh per block.
__global__ __launch_bounds__(512, 2)
void gemm1_kernel(const unsigned short* __restrict__ Ab, const unsigned short* __restrict__ Bt,
                  const unsigned short* __restrict__ WshT, const float* __restrict__ b1,
                  float* __restrict__ part) {
  __shared__ unsigned short sT[2][2][2][8192];  // [dbuf][A=0/B=1][ks] 128KB
  const int tid  = threadIdx.x;
  const int wave = tid >> 6, lane = tid & 63;
  const int wm = wave >> 2, wn = wave & 3;      // 2M x 4N waves, wave tile 128x64
  const int b = blockIdx.x;                     // 256 blocks
  const int tile = (b & 7) * 32 + (b >> 3);     // XCD-chunked bijection
  const int mtile = tile >> 2, ntile = tile & 3;
  const int rowBase = mtile * 256, colBase = ntile * 256;

  f32x4 acc[8][4] = {};
  bf16x8 a0[4], a1[4];   // current A quadrant, ks0/ks1 (mi0 in P1-2, mi1 in P3-4)
  bf16x8 b0[2], b1v[2];  // B ni0, ks0/ks1
  bf16x8 c0[2], c1[2];   // B ni1, ks0/ks1

  const int lrow0 = wave * 16 + (lane >> 3);
  const int q     = (lane & 7) ^ (lrow0 & 7);
  const unsigned short* gA = Ab + (size_t)(rowBase + lrow0 * 2 + (q >> 2)) * DIN + (q & 3) * 8;
  const unsigned short* gB = Bt + (size_t)(colBase + lrow0 * 2 + (q >> 2)) * DIN + (q & 3) * 8;
  const int ldOff = wave * 1024;

  const int frow = lane & 15, hi = lane >> 4, fr2 = frow >> 1;
  const int pp    = ((frow & 1) * 4 + hi) ^ fr2;
  const int aBase = (wm * 64 + fr2) * 64 + pp * 8;
  const int bBase = (wn * 32 + fr2) * 64 + pp * 8;

#define STAGE(opv, db, ksv, kt) do {                                        \
    const unsigned short* g_ = ((opv) ? gB : gA) + (kt) * 64 + (ksv) * 32;  \
    unsigned short* l_ = &sT[db][opv][ksv][ldOff];                          \
    gload_lds16(g_, l_);                                                    \
    gload_lds16(g_ + (size_t)16 * DIN, l_ + 512);                           \
  } while (0)
#define RDA4(db, ksv, mq, dst) do {                                         \
    const unsigned short* s_ = &sT[db][0][ksv][aBase + (mq) * 2048];        \
    dst[0] = *(const bf16x8*)(s_);        dst[1] = *(const bf16x8*)(s_ + 512); \
    dst[2] = *(const bf16x8*)(s_ + 1024); dst[3] = *(const bf16x8*)(s_ + 1536); \
  } while (0)
#define RDB2(db, ksv, ni, dst) do {                                         \
    const unsigned short* s_ = &sT[db][1][ksv][bBase + (ni) * 1024];        \
    dst[0] = *(const bf16x8*)(s_);        dst[1] = *(const bf16x8*)(s_ + 512); \
  } while (0)
#define MMQ(MB, NB0, X0, X1) do {                                           \
    __builtin_amdgcn_s_setprio(1);                                          \
    _Pragma("unroll") for (int mm = 0; mm < 4; ++mm)                        \
    _Pragma("unroll") for (int nn = 0; nn < 2; ++nn) {                      \
      acc[(MB)+mm][(NB0)+nn] = __builtin_amdgcn_mfma_f32_16x16x32_bf16(     \
          a0[mm], X0[nn], acc[(MB)+mm][(NB0)+nn], 0, 0, 0);                 \
      acc[(MB)+mm][(NB0)+nn] = __builtin_amdgcn_mfma_f32_16x16x32_bf16(     \
          a1[mm], X1[nn], acc[(MB)+mm][(NB0)+nn], 0, 0, 0);                 \
    }                                                                       \
    __builtin_amdgcn_s_setprio(0);                                          \
  } while (0)
#define FENCE asm volatile("" ::: "memory")
#define BARP do { FENCE; __builtin_amdgcn_s_barrier();                      \
                  __builtin_amdgcn_sched_barrier(0); } while (0)

  // prologue: ks0(0)A,B ; ks1(0)A,B ; ks0(1)A,B — vmcnt(2) drains tile0 only
  STAGE(0, 0, 0, 0); STAGE(1, 0, 0, 0);
  STAGE(0, 0, 1, 0); STAGE(1, 0, 1, 0);
  STAGE(0, 1, 0, 1); STAGE(1, 1, 0, 1);
  asm volatile("s_waitcnt vmcnt(2)" ::: "memory");
  BARP;

  const int NT = DIN / 64;  // 32
#pragma unroll 2
  for (int t = 0; t < NT; ++t) {
    const int db = t & 1, dn = db ^ 1;
    // P1: Q(mi0,ni0) — 12 reads
    RDA4(db, 0, 0, a0); RDA4(db, 1, 0, a1);
    RDB2(db, 0, 0, b0); RDB2(db, 1, 0, b1v);
    if (t < NT - 1) STAGE(0, dn, 1, t + 1);
    BARP;
    MMQ(0, 0, b0, b1v);
    BARP;
    // P2: Q(mi0,ni1) — 4 reads
    RDB2(db, 0, 1, c0); RDB2(db, 1, 1, c1);
    if (t < NT - 1) STAGE(1, dn, 1, t + 1);
    BARP;
    MMQ(0, 2, c0, c1);
    BARP;
    // P3: Q(mi1,ni0) — 8 reads
    RDA4(db, 0, 1, a0); RDA4(db, 1, 1, a1);
    BARP;
    MMQ(4, 0, b0, b1v);
    BARP;
    // P4: Q(mi1,ni1) — 0 reads; stage ks0(t+2) both ops
    if (t < NT - 2) { STAGE(0, db, 0, t + 2); STAGE(1, db, 0, t + 2); }
    BARP;
    MMQ(4, 2, c0, c1);
    if (t < NT - 2)       asm volatile("s_waitcnt vmcnt(4)" ::: "memory");
    else if (t == NT - 2) asm volatile("s_waitcnt vmcnt(0)" ::: "memory");
    BARP;
  }
#undef STAGE
#undef RDA4
#undef RDB2
#undef MMQ

  // ================= fused epilogue (r11, verified) =================
  const int ec0l = wn * 64 + frow;
  float bv[4];
#pragma unroll
  for (int n = 0; n < 4; ++n) bv[n] = b1[colBase + ec0l + n * 16];

  unsigned short* sX = (unsigned short*)sT;  // 64KB: [128 lrows][32 chunks of 8 bf16]
  BARP;

#pragma unroll
  for (int h = 0; h < 2; ++h) {
#pragma unroll
    for (int mm = 0; mm < 4; ++mm) {
#pragma unroll
      for (int n = 0; n < 4; ++n) {
#pragma unroll
        for (int r = 0; r < 4; ++r) {
          float v = acc[h * 4 + mm][n][r] + bv[n];
          v = v > 0.f ? v : expm1f(v);
          const int lrow = wm * 64 + mm * 16 + hi * 4 + r;   // 0..127
          const int cel  = ec0l + n * 16;                    // local col 0..255
          const int p    = (cel >> 3) ^ SW(lrow & 15);
          sX[lrow * 256 + p * 8 + (cel & 7)] = f2bf(v);
        }
      }
    }
    BARP;
    f32x4 acc2[2] = {};
    const int rb = wave * 16;
#pragma unroll
    for (int ks = 0; ks < 8; ++ks) {
      const int p = (ks * 4 + hi) ^ SW(frow);
      bf16x8 xa = *(const bf16x8*)&sX[(rb + frow) * 256 + p * 8];
      bf16x8 w0 = *(const bf16x8*)(WshT + (size_t)frow * DFC + colBase + ks * 32 + hi * 8);
      bf16x8 w1 = *(const bf16x8*)(WshT + (size_t)(16 + frow) * DFC + colBase + ks * 32 + hi * 8);
      acc2[0] = __builtin_amdgcn_mfma_f32_16x16x32_bf16(xa, w0, acc2[0], 0, 0, 0);
      acc2[1] = __builtin_amdgcn_mfma_f32_16x16x32_bf16(xa, w1, acc2[1], 0, 0, 0);
    }
#pragma unroll
    for (int jf = 0; jf < 2; ++jf) {
      const int j = jf * 16 + frow;
      if (j < 20) {
#pragma unroll
        for (int r = 0; r < 4; ++r) {
          const int lrow = rb + hi * 4 + r;                  // 0..127
          const int grow = rowBase + h * 64 + (lrow & 63) + (lrow >> 6) * 128;
          part[(size_t)ntile * (B_ * 20) + (size_t)grow * 20 + j] = acc2[jf][r];
        }
      }
    }
    BARP;
  }
}

// ---------------- K2: reduce partials + bias -> d_out (mode | log_std) ----------------
__global__ __launch_bounds__(256)
void reduce2_kernel(const float* __restrict__ part, const float* __restrict__ bsh,
                    float* __restrict__ out) {
  const int idx = blockIdx.x * 256 + threadIdx.x;  // 1280 blocks x 256 = 327680
  if (idx >= B_ * 20) return;
  const int row = idx / 20, j = idx - row * 20;
  float s = bsh[j];
#pragma unroll
  for (int t = 0; t < 4; ++t) s += part[(size_t)t * (B_ * 20) + idx];
  const int jj = j < 10 ? j : j - 10;
  const size_t base = (j < 10) ? (size_t)0 : (size_t)B_ * NB_;
  out[base + (size_t)row * NB_ + jj] = s;
}

// ---------------- K3: samples = mode + exp(log_std) * noise ----------------
__global__ __launch_bounds__(256)
void sample_kernel(const float* __restrict__ noise, float* __restrict__ out) {
  __shared__ float sm[4][NB_], se[4][NB_];
  const int tid  = threadIdx.x;
  const int wave = tid >> 6, lane = tid & 63;
  const int row  = blockIdx.x * 4 + wave;
  if (lane < NB_) {
    sm[wave][lane] = out[(size_t)row * NB_ + lane];
    se[wave][lane] = expf(out[(size_t)B_ * NB_ + (size_t)row * NB_ + lane]);
  }
  __syncthreads();
  const f32x4* np4 = (const f32x4*)(noise + (size_t)row * (S_ * NB_));
  f32x4*       op4 = (f32x4*)(out + (size_t)2 * B_ * NB_ + (size_t)row * (S_ * NB_));
#pragma unroll
  for (int it = 0; it < (S_ * NB_) / 256; ++it) {   // 10 iters
    f32x4 nv = np4[it * 64 + lane];
    int j0 = (lane * 4 + it * 6) % 10;
    int j1 = j0 + 1; if (j1 >= 10) j1 -= 10;
    int j2 = j1 + 1; if (j2 >= 10) j2 -= 10;
    int j3 = j2 + 1; if (j3 >= 10) j3 -= 10;
    f32x4 r;
    r[0] = sm[wave][j0] + se[wave][j0] * nv[0];
    r[1] = sm[wave][j1] + se[wave][j1] * nv[1];
    r[2] = sm[wave][j2] + se[wave][j2] * nv[2];
    r[3] = sm[wave][j3] + se[wave][j3] * nv[3];
    op4[it * 64 + lane] = r;
  }
}

extern "C" void kernel_launch(void* const* d_in, const int* in_sizes, int n_in,
                              void* d_out, int out_size, void* d_ws, size_t ws_size,
                              hipStream_t stream) {
  const float* A     = (const float*)d_in[0];  // [16384][2048]
  const float* W1    = (const float*)d_in[1];  // [2048][1024]
  const float* b1    = (const float*)d_in[2];  // [1024]
  const float* Wsh   = (const float*)d_in[3];  // [1024][20]
  const float* bsh   = (const float*)d_in[4];  // [20]
  const float* noise = (const float*)d_in[5];  // [16384][256][10]
  float* out = (float*)d_out;                  // mode | log_std | samples

  unsigned short* Wt   = (unsigned short*)d_ws;        // bf16 [1024][2048] = 4 MB
  unsigned short* WshT = Wt + (size_t)DFC * DIN;       // bf16 [32][1024] = 64 KB
  const size_t wsNeed = (size_t)DFC * DIN * 2 + 65536 +
                        (size_t)4 * B_ * 20 * 4 + (size_t)B_ * DIN * 2;
  float* part;
  unsigned short* Ab;
  if (ws_size >= wsNeed) {
    part = (float*)(WshT + 32 * 1024);
    Ab   = (unsigned short*)(part + (size_t)4 * B_ * 20);
  } else {
    part = out + (size_t)2 * B_ * NB_;
    Ab   = (unsigned short*)(part + (size_t)4 * B_ * 20);
  }

  convT_kernel<<<dim3(DFC / 32, DIN / 32), 256, 0, stream>>>(W1, Wt);
  convW2_kernel<<<dim3(128), 256, 0, stream>>>(Wsh, WshT);
  convA_kernel<<<dim3(2048), 256, 0, stream>>>(A, Ab);
  gemm1_kernel<<<dim3((B_ / 256) * (DFC / 256)), 512, 0, stream>>>(Ab, Wt, WshT, b1, part);
  reduce2_kernel<<<dim3((B_ * 20 + 255) / 256), 256, 0, stream>>>(part, bsh, out);
  sample_kernel<<<dim3(B_ / 4), 256, 0, stream>>>(noise, out);
}